// Round 8
// baseline (168.147 us; speedup 1.0000x reference)
//
#include <hip/hip_runtime.h>
#include <stdint.h>

#define WAVE 64
#define CIN 64
#define COUT 64
#define KS 5
#define KTOT 125  // 5^3
#define XPAD 68   // LDS row pad: breaks mod-32 bank degeneracy, keeps 16B align

__device__ inline unsigned long long wmin64(unsigned long long v) {
#pragma unroll
  for (int o = 32; o >= 1; o >>= 1) {
    unsigned long long u = __shfl_xor(v, o, 64);
    v = (u < v) ? u : v;
  }
  return v;
}

__device__ inline float wmin64f(float v) {
#pragma unroll
  for (int o = 32; o >= 1; o >>= 1) {
    float u = __shfl_xor(v, o, 64);
    v = fminf(v, u);
  }
  return v;
}

__device__ inline unsigned f32_orderable(float f) {
  unsigned fb = __float_as_uint(f);
  return (fb & 0x80000000u) ? ~fb : (fb | 0x80000000u);
}
__device__ inline float f32_unorderable(unsigned u) {
  unsigned fb = (u & 0x80000000u) ? (u & 0x7fffffffu) : ~u;
  return __uint_as_float(fb);
}

__device__ inline unsigned short f2bf(float f) {  // RNE
  unsigned u = __float_as_uint(f);
  unsigned r = (u + 0x7fffu + ((u >> 16) & 1u)) >> 16;
  return (unsigned short)r;
}
__device__ inline float bf2f(unsigned short v) {
  return __uint_as_float(((unsigned)v) << 16);
}

__device__ inline void edge_basis(const float* __restrict__ pseudo, int e,
                                  float bas[8], int kidx[8]) {
  float v0 = pseudo[e * 3 + 0] * (float)(KS - 1);
  float v1 = pseudo[e * 3 + 1] * (float)(KS - 1);
  float v2 = pseudo[e * 3 + 2] * (float)(KS - 1);
  float l0 = floorf(v0), l1 = floorf(v1), l2 = floorf(v2);
  float f0 = v0 - l0, f1 = v1 - l1, f2 = v2 - l2;
  int i0 = (int)l0, i1 = (int)l1, i2 = (int)l2;
#pragma unroll
  for (int s = 0; s < 8; s++) {
    int b0 = s & 1, b1 = (s >> 1) & 1, b2 = (s >> 2) & 1;
    float bb = (b0 ? f0 : 1.f - f0) * (b1 ? f1 : 1.f - f1) * (b2 ? f2 : 1.f - f2);
    int j0 = i0 + b0; j0 = j0 < 0 ? 0 : (j0 > KS - 1 ? KS - 1 : j0);
    int j1 = i1 + b1; j1 = j1 < 0 ? 0 : (j1 > KS - 1 ? KS - 1 : j1);
    int j2 = i2 + b2; j2 = j2 < 0 ? 0 : (j2 > KS - 1 ? KS - 1 : j2);
    bas[s] = bb;
    kidx[s] = j0 + KS * j1 + KS * KS * j2;
  }
}

// ---------- S1: xW[n,k,:] = x[n] @ W[k] — batched GEMM, bf16 plain stores ----------
__global__ __launch_bounds__(256) void xw_gemm_kernel(const float* __restrict__ x,
                                                      const float* __restrict__ Wf,
                                                      unsigned short* __restrict__ xw,
                                                      int Nx_) {
  __shared__ float Xs[64][XPAD];  // row-major [row][i]
  __shared__ float Wt[64][XPAD];  // [i][o]
  int tid = threadIdx.x;
  int n0 = blockIdx.x * 64;
  int k = blockIdx.y;

  // stage W[k] — float4, padded rows
  {
    int wi = tid >> 2, wo = (tid & 3) * 16;
    const float* wsrc = Wf + (size_t)k * (CIN * COUT) + wi * COUT + wo;
    float4 a = *(const float4*)wsrc;
    float4 b = *(const float4*)(wsrc + 4);
    float4 c = *(const float4*)(wsrc + 8);
    float4 d = *(const float4*)(wsrc + 12);
    *(float4*)&Wt[wi][wo + 0] = a;
    *(float4*)&Wt[wi][wo + 4] = b;
    *(float4*)&Wt[wi][wo + 8] = c;
    *(float4*)&Wt[wi][wo + 12] = d;
  }
  // stage X row-major — float4 writes (no transpose; compute uses broadcast reads)
  {
    int rec = tid >> 2, c16 = (tid & 3) * 16;
    int row = n0 + rec;
    if (row >= Nx_) row = Nx_ - 1;
    const float* xs = x + (size_t)row * CIN + c16;
    float4 v0 = *(const float4*)xs;
    float4 v1 = *(const float4*)(xs + 4);
    float4 v2 = *(const float4*)(xs + 8);
    float4 v3 = *(const float4*)(xs + 12);
    *(float4*)&Xs[rec][c16 + 0] = v0;
    *(float4*)&Xs[rec][c16 + 4] = v1;
    *(float4*)&Xs[rec][c16 + 8] = v2;
    *(float4*)&Xs[rec][c16 + 12] = v3;
  }
  __syncthreads();

  int mg = tid >> 4, og = tid & 15;
  int m = mg * 4, o = og * 4;
  float a_[4][4] = {};
#pragma unroll 16
  for (int kk = 0; kk < 64; kk++) {
    float4 wv = *(const float4*)&Wt[kk][o];
    float x0 = Xs[m + 0][kk];  // 4 distinct addrs/wave -> LDS broadcast, conflict-free
    float x1 = Xs[m + 1][kk];
    float x2 = Xs[m + 2][kk];
    float x3 = Xs[m + 3][kk];
    a_[0][0] = fmaf(x0, wv.x, a_[0][0]);
    a_[0][1] = fmaf(x0, wv.y, a_[0][1]);
    a_[0][2] = fmaf(x0, wv.z, a_[0][2]);
    a_[0][3] = fmaf(x0, wv.w, a_[0][3]);
    a_[1][0] = fmaf(x1, wv.x, a_[1][0]);
    a_[1][1] = fmaf(x1, wv.y, a_[1][1]);
    a_[1][2] = fmaf(x1, wv.z, a_[1][2]);
    a_[1][3] = fmaf(x1, wv.w, a_[1][3]);
    a_[2][0] = fmaf(x2, wv.x, a_[2][0]);
    a_[2][1] = fmaf(x2, wv.y, a_[2][1]);
    a_[2][2] = fmaf(x2, wv.z, a_[2][2]);
    a_[2][3] = fmaf(x2, wv.w, a_[2][3]);
    a_[3][0] = fmaf(x3, wv.x, a_[3][0]);
    a_[3][1] = fmaf(x3, wv.y, a_[3][1]);
    a_[3][2] = fmaf(x3, wv.z, a_[3][2]);
    a_[3][3] = fmaf(x3, wv.w, a_[3][3]);
  }

  // bf16 store: xw[(row*125 + k)*64 + o..o+3]
#pragma unroll
  for (int i = 0; i < 4; i++) {
    int row = n0 + m + i;
    if (row < Nx_) {
      ushort4 v = make_ushort4(f2bf(a_[i][0]), f2bf(a_[i][1]),
                               f2bf(a_[i][2]), f2bf(a_[i][3]));
      *(ushort4*)&xw[((size_t)row * KTOT + k) * COUT + o] = v;
    }
  }
}

// ---------- S2: per-edge gather-sum (bf16 reads) + single atomic burst ----------
__global__ void edge_sum_kernel(const int* __restrict__ ei,
                                const float* __restrict__ pseudo,
                                const unsigned short* __restrict__ xw,
                                float* __restrict__ acc,
                                float* __restrict__ deg, int E_) {
  int lane = threadIdx.x & 63;
  int e = (int)((blockIdx.x * blockDim.x + threadIdx.x) >> 6);
  if (e >= E_) return;
  int src = ei[e];
  int dst = ei[E_ + e];
  float bas[8];
  int kidx[8];
  edge_basis(pseudo, e, bas, kidx);

  const unsigned short* bx = xw + (size_t)src * (KTOT * COUT) + lane;
  float y = 0.f;
#pragma unroll
  for (int s = 0; s < 8; s++) {
    y = fmaf(bas[s], bf2f(bx[kidx[s] * COUT]), y);
  }
  atomicAdd(&acc[(size_t)dst * COUT + lane], y);
  if (lane == 0) atomicAdd(&deg[dst], 1.f);
}

// ---------- node finish: acc/deg + x@root + bias, ELU ----------
__global__ void node_finish_kernel(const float* __restrict__ x,
                                   const float* __restrict__ root,
                                   const float* __restrict__ bias,
                                   const float* __restrict__ acc,
                                   const float* __restrict__ deg,
                                   float* __restrict__ h, int Nx_) {
  int lane = threadIdx.x & 63;
  int n = (int)((blockIdx.x * blockDim.x + threadIdx.x) >> 6);
  if (n >= Nx_) return;
  float xs = x[(size_t)n * CIN + lane];
  float r = 0.f;
#pragma unroll 4
  for (int i = 0; i < CIN; i++) {
    float xv = __shfl(xs, i, 64);
    r = fmaf(xv, root[i * COUT + lane], r);
  }
  float d = deg[n];
  d = d > 1.f ? d : 1.f;
  float o = acc[(size_t)n * COUT + lane] / d + r + bias[lane];
  h[(size_t)n * COUT + lane] = (o > 0.f) ? o : expm1f(o);
}

// ---------- kNN pre-pack: [x0,x1,x2,|x|^2] ----------
__global__ void pack_posx_kernel(const float* __restrict__ pos_x,
                                 float4* __restrict__ pxp, int Nx_) {
  int t = blockIdx.x * blockDim.x + threadIdx.x;
  if (t >= Nx_) return;
  float a0 = pos_x[t * 3 + 0], a1 = pos_x[t * 3 + 1], a2 = pos_x[t * 3 + 2];
  pxp[t] = make_float4(a0, a1, a2, a0 * a0 + a1 * a1 + a2 * a2);
}

// ---------- fused kNN + inverse-distance interp (k<=3 gated path) ----------
__global__ void knn_interp2_kernel(const float* __restrict__ h,
                                   const float4* __restrict__ pxp,
                                   const float* __restrict__ pos_y,
                                   const int* __restrict__ batch_x,
                                   const int* __restrict__ batch_y,
                                   const int* __restrict__ kptr,
                                   float* __restrict__ out,
                                   int Nx_, int Ny_) {
  int lane = threadIdx.x & 63;
  int yy = (int)((blockIdx.x * blockDim.x + threadIdx.x) >> 6);
  if (yy >= Ny_) return;

  float q0 = pos_y[yy * 3 + 0], q1 = pos_y[yy * 3 + 1], q2 = pos_y[yy * 3 + 2];
  float py2 = q0 * q0 + q1 * q1 + q2 * q2;
  int by = batch_y[yy];
  int kk = *kptr;
  kk = kk < 1 ? 1 : (kk > 8 ? 8 : kk);

  float num = 0.f, den = 0.f;

  if (kk <= 3) {
    const float FINF = __uint_as_float(0x7f800000u);
    float bd0 = FINF, bd1 = FINF, bd2 = FINF;
    unsigned bi0 = ~0u, bi1 = ~0u, bi2 = ~0u;
    // U = wave-min of per-lane 3rd-best: upper bound on global 3rd-best.
    // Skipping d2 >= U provably never drops a global-top-3 element.
    float U = FINF;

    for (int t0 = 0; t0 < Nx_; t0 += 64) {
      int t = t0 + lane;
      int tc = t < Nx_ ? t : Nx_ - 1;
      float4 p = pxp[tc];
      float dot = fmaf(q0, p.x, fmaf(q1, p.y, q2 * p.z));
      float d2 = fmaf(-2.f, dot, py2 + p.w);
      if (batch_x[tc] != by) d2 = 1e10f;
      if (t >= Nx_) d2 = FINF;

      if (__any(d2 < U)) {  // wave-uniform gate; ~80% skip after warm-up
        float kv = d2;
        unsigned ki = (unsigned)t;
        {
          bool lt = kv < bd0;
          float nv = lt ? kv : bd0; float xv = lt ? bd0 : kv;
          unsigned ni = lt ? ki : bi0; unsigned xi = lt ? bi0 : ki;
          bd0 = nv; bi0 = ni; kv = xv; ki = xi;
        }
        {
          bool lt = kv < bd1;
          float nv = lt ? kv : bd1; float xv = lt ? bd1 : kv;
          unsigned ni = lt ? ki : bi1; unsigned xi = lt ? bi1 : ki;
          bd1 = nv; bi1 = ni; kv = xv; ki = xi;
        }
        {
          bool lt = kv < bd2;
          float nv = lt ? kv : bd2;
          unsigned ni = lt ? ki : bi2;
          bd2 = nv; bi2 = ni;
        }
      }
      if ((t0 & 448) == 448) U = wmin64f(bd2);  // refresh every 8 iters
    }

    unsigned long long c0 = (((unsigned long long)f32_orderable(bd0)) << 32) | bi0;
    unsigned long long c1 = (((unsigned long long)f32_orderable(bd1)) << 32) | bi1;
    unsigned long long c2 = (((unsigned long long)f32_orderable(bd2)) << 32) | bi2;

    for (int j = 0; j < kk; j++) {
      unsigned long long m = wmin64(c0);
      if (c0 == m) { c0 = c1; c1 = c2; c2 = ~0ull; }
      unsigned u = (unsigned)(m >> 32);
      int idx = (int)(m & 0xffffffffu);
      idx = (idx < 0 || idx >= Nx_) ? 0 : idx;
      float d2 = f32_unorderable(u);
      float w = 1.f / fmaxf(d2, 1e-16f);
      num = fmaf(w, h[(size_t)idx * COUT + lane], num);
      den += w;
    }
  } else {
    unsigned long long best[8];
#pragma unroll
    for (int j = 0; j < 8; j++) best[j] = ~0ull;

    for (int t0 = 0; t0 < Nx_; t0 += 64) {
      int t = t0 + lane;
      unsigned long long key = ~0ull;
      if (t < Nx_) {
        float4 p = pxp[t];
        float dot = fmaf(q0, p.x, fmaf(q1, p.y, q2 * p.z));
        float d2 = fmaf(-2.f, dot, py2 + p.w);
        if (batch_x[t] != by) d2 = 1e10f;
        key = (((unsigned long long)f32_orderable(d2)) << 32) | (unsigned)t;
      }
      if (key < best[7]) {
#pragma unroll
        for (int j = 0; j < 8; j++) {
          unsigned long long mn = key < best[j] ? key : best[j];
          unsigned long long mx = key < best[j] ? best[j] : key;
          best[j] = mn;
          key = mx;
        }
      }
    }

    for (int j = 0; j < kk; j++) {
      unsigned long long m = wmin64(best[0]);
      if (best[0] == m) {
#pragma unroll
        for (int t = 0; t < 7; t++) best[t] = best[t + 1];
        best[7] = ~0ull;
      }
      unsigned u = (unsigned)(m >> 32);
      int idx = (int)(m & 0xffffffffu);
      idx = (idx < 0 || idx >= Nx_) ? 0 : idx;
      float d2 = f32_unorderable(u);
      float w = 1.f / fmaxf(d2, 1e-16f);
      num = fmaf(w, h[(size_t)idx * COUT + lane], num);
      den += w;
    }
  }

  out[(size_t)yy * COUT + lane] = num / den;
}

extern "C" void kernel_launch(void* const* d_in, const int* in_sizes, int n_in,
                              void* d_out, int out_size, void* d_ws, size_t ws_size,
                              hipStream_t stream) {
  const float* x = (const float*)d_in[0];
  const float* pos_x = (const float*)d_in[1];
  const float* pos_y = (const float*)d_in[2];
  const int* eidx = (const int*)d_in[3];
  const float* pseudo = (const float*)d_in[4];
  const int* batch_x = (const int*)d_in[5];
  const int* batch_y = (const int*)d_in[6];
  const float* W = (const float*)d_in[7];   // [125,64,64]
  const float* root = (const float*)d_in[8];
  const float* bias = (const float*)d_in[9];
  const int* kptr = (const int*)d_in[10];

  int Nx = in_sizes[0] / CIN;
  int Ny = in_sizes[2] / 3;
  int E = in_sizes[3] / 2;

  // ws layout (4B units): acc[Nx*64] | deg[Nx] | h[Nx*64] | pxp[Nx*4] | xw[bf16 Nx*125*64]
  float* acc = (float*)d_ws;
  float* deg = acc + (size_t)Nx * COUT;
  float* h = deg + Nx;
  float4* pxp = (float4*)(h + (size_t)Nx * COUT);
  unsigned short* xw = (unsigned short*)(pxp + Nx);

  float* out = (float*)d_out;

  // zero acc + deg (contiguous); xw fully written by xw_gemm
  hipMemsetAsync(acc, 0, ((size_t)Nx * COUT + Nx) * sizeof(float), stream);

  {
    dim3 grid((Nx + 63) / 64, KTOT);
    xw_gemm_kernel<<<grid, 256, 0, stream>>>(x, W, xw, Nx);
  }
  {
    int blocks = (E * WAVE + 255) / 256;
    edge_sum_kernel<<<blocks, 256, 0, stream>>>(eidx, pseudo, xw, acc, deg, E);
  }
  {
    int blocks = (Nx * WAVE + 255) / 256;
    node_finish_kernel<<<blocks, 256, 0, stream>>>(x, root, bias, acc, deg, h, Nx);
  }
  pack_posx_kernel<<<(Nx + 255) / 256, 256, 0, stream>>>(pos_x, pxp, Nx);
  {
    int blocks = (Ny * WAVE + 255) / 256;
    knn_interp2_kernel<<<blocks, 256, 0, stream>>>(h, pxp, pos_y, batch_x, batch_y,
                                                   kptr, out, Nx, Ny);
  }
}

// Round 9
// 151.404 us; speedup vs baseline: 1.1106x; 1.1106x over previous
//
#include <hip/hip_runtime.h>
#include <stdint.h>

#define WAVE 64
#define CIN 64
#define COUT 64
#define KS 5
#define KTOT 125  // 5^3

typedef __attribute__((ext_vector_type(8))) short short8v;  // 8 bf16 = 4 VGPRs
typedef __attribute__((ext_vector_type(4))) float f32x4;

__device__ inline unsigned long long wmin64(unsigned long long v) {
#pragma unroll
  for (int o = 32; o >= 1; o >>= 1) {
    unsigned long long u = __shfl_xor(v, o, 64);
    v = (u < v) ? u : v;
  }
  return v;
}

__device__ inline float wmin64f(float v) {
#pragma unroll
  for (int o = 32; o >= 1; o >>= 1) {
    float u = __shfl_xor(v, o, 64);
    v = fminf(v, u);
  }
  return v;
}

__device__ inline unsigned f32_orderable(float f) {
  unsigned fb = __float_as_uint(f);
  return (fb & 0x80000000u) ? ~fb : (fb | 0x80000000u);
}
__device__ inline float f32_unorderable(unsigned u) {
  unsigned fb = (u & 0x80000000u) ? (u & 0x7fffffffu) : ~u;
  return __uint_as_float(fb);
}

__device__ inline unsigned short f2bf(float f) {  // RNE
  unsigned u = __float_as_uint(f);
  unsigned r = (u + 0x7fffu + ((u >> 16) & 1u)) >> 16;
  return (unsigned short)r;
}
__device__ inline float bf2f(unsigned short v) {
  return __uint_as_float(((unsigned)v) << 16);
}

__device__ inline void edge_basis(const float* __restrict__ pseudo, int e,
                                  float bas[8], int kidx[8]) {
  float v0 = pseudo[e * 3 + 0] * (float)(KS - 1);
  float v1 = pseudo[e * 3 + 1] * (float)(KS - 1);
  float v2 = pseudo[e * 3 + 2] * (float)(KS - 1);
  float l0 = floorf(v0), l1 = floorf(v1), l2 = floorf(v2);
  float f0 = v0 - l0, f1 = v1 - l1, f2 = v2 - l2;
  int i0 = (int)l0, i1 = (int)l1, i2 = (int)l2;
#pragma unroll
  for (int s = 0; s < 8; s++) {
    int b0 = s & 1, b1 = (s >> 1) & 1, b2 = (s >> 2) & 1;
    float bb = (b0 ? f0 : 1.f - f0) * (b1 ? f1 : 1.f - f1) * (b2 ? f2 : 1.f - f2);
    int j0 = i0 + b0; j0 = j0 < 0 ? 0 : (j0 > KS - 1 ? KS - 1 : j0);
    int j1 = i1 + b1; j1 = j1 < 0 ? 0 : (j1 > KS - 1 ? KS - 1 : j1);
    int j2 = i2 + b2; j2 = j2 < 0 ? 0 : (j2 > KS - 1 ? KS - 1 : j2);
    bas[s] = bb;
    kidx[s] = j0 + KS * j1 + KS * KS * j2;
  }
}

// ---------- C0: x -> bf16 (coalesced float4 -> ushort4) ----------
__global__ void cvtx_kernel(const float* __restrict__ x,
                            unsigned short* __restrict__ xbf, int n4) {
  int i = blockIdx.x * blockDim.x + threadIdx.x;
  if (i >= n4) return;
  float4 v = *(const float4*)&x[i * 4];
  *(ushort4*)&xbf[i * 4] =
      make_ushort4(f2bf(v.x), f2bf(v.y), f2bf(v.z), f2bf(v.w));
}

// ---------- C1: W[k][i][o] -> wbf[k][o][i] bf16 (LDS transpose, 1 block/k) ----------
__global__ __launch_bounds__(256) void cvtw_kernel(const float* __restrict__ Wf,
                                                   unsigned short* __restrict__ wbf) {
  __shared__ float L[64][68];
  int k = blockIdx.x;
  int tid = threadIdx.x;
  {
    int i = tid >> 2, o0 = (tid & 3) * 16;
    const float* src = Wf + (size_t)k * 4096 + i * 64 + o0;
    float4 a = *(const float4*)src;
    float4 b = *(const float4*)(src + 4);
    float4 c = *(const float4*)(src + 8);
    float4 d = *(const float4*)(src + 12);
    *(float4*)&L[i][o0 + 0] = a;
    *(float4*)&L[i][o0 + 4] = b;
    *(float4*)&L[i][o0 + 8] = c;
    *(float4*)&L[i][o0 + 12] = d;
  }
  __syncthreads();
  int o = tid >> 2, i0 = (tid & 3) * 16;
  unsigned short* dst = wbf + (size_t)k * 4096 + o * 64 + i0;
#pragma unroll
  for (int g = 0; g < 4; g++) {
    *(ushort4*)&dst[g * 4] =
        make_ushort4(f2bf(L[i0 + g * 4 + 0][o]), f2bf(L[i0 + g * 4 + 1][o]),
                     f2bf(L[i0 + g * 4 + 2][o]), f2bf(L[i0 + g * 4 + 3][o]));
  }
}

// ---------- S1: xw[n,k,:] = x[n] @ W[k] via MFMA (no LDS; L2-resident inputs) ----------
__global__ __launch_bounds__(256) void xw_mfma_kernel(
    const unsigned short* __restrict__ xbf,   // [Nx][64] bf16
    const unsigned short* __restrict__ wbf,   // [125][o][i] bf16 (B^T, k-contig)
    unsigned short* __restrict__ xw, int Nx_) {
  int tid = threadIdx.x;
  int w = tid >> 6, lane = tid & 63;
  int n0 = blockIdx.x * 64;
  int k = blockIdx.y;
  int row16 = n0 + w * 16;

  int lr = lane & 15, kg = lane >> 4;  // A row / B col = lr; k-group = kg
  int rA = row16 + lr;
  if (rA >= Nx_) rA = Nx_ - 1;  // dup-read guard (stores guarded below)

  // A fragments: 8 contiguous k at kg*8 (ks=0) and 32+kg*8 (ks=1)
  short8v a0 = *(const short8v*)&xbf[(size_t)rA * CIN + kg * 8];
  short8v a1 = *(const short8v*)&xbf[(size_t)rA * CIN + 32 + kg * 8];

  const unsigned short* wb = wbf + (size_t)k * 4096;
  f32x4 acc[4];
#pragma unroll
  for (int ct = 0; ct < 4; ct++) {
    int col = ct * 16 + lr;
    short8v b0 = *(const short8v*)&wb[col * 64 + kg * 8];
    short8v b1 = *(const short8v*)&wb[col * 64 + 32 + kg * 8];
    f32x4 c = {0.f, 0.f, 0.f, 0.f};
    c = __builtin_amdgcn_mfma_f32_16x16x32_bf16(a0, b0, c, 0, 0, 0);
    c = __builtin_amdgcn_mfma_f32_16x16x32_bf16(a1, b1, c, 0, 0, 0);
    acc[ct] = c;
  }

  // D layout: col = lane&15, row = (lane>>4)*4 + reg  -> bf16 store
#pragma unroll
  for (int ct = 0; ct < 4; ct++) {
#pragma unroll
    for (int r = 0; r < 4; r++) {
      int row = row16 + kg * 4 + r;
      if (row < Nx_) {
        xw[((size_t)row * KTOT + k) * COUT + ct * 16 + lr] = f2bf(acc[ct][r]);
      }
    }
  }
}

// ---------- S2: per-edge gather-sum (bf16 reads) + single atomic burst ----------
__global__ void edge_sum_kernel(const int* __restrict__ ei,
                                const float* __restrict__ pseudo,
                                const unsigned short* __restrict__ xw,
                                float* __restrict__ acc,
                                float* __restrict__ deg, int E_) {
  int lane = threadIdx.x & 63;
  int e = (int)((blockIdx.x * blockDim.x + threadIdx.x) >> 6);
  if (e >= E_) return;
  int src = ei[e];
  int dst = ei[E_ + e];
  float bas[8];
  int kidx[8];
  edge_basis(pseudo, e, bas, kidx);

  const unsigned short* bx = xw + (size_t)src * (KTOT * COUT) + lane;
  float y = 0.f;
#pragma unroll
  for (int s = 0; s < 8; s++) {
    y = fmaf(bas[s], bf2f(bx[kidx[s] * COUT]), y);
  }
  atomicAdd(&acc[(size_t)dst * COUT + lane], y);
  if (lane == 0) atomicAdd(&deg[dst], 1.f);
}

// ---------- node finish: acc/deg + x@root + bias, ELU ----------
__global__ void node_finish_kernel(const float* __restrict__ x,
                                   const float* __restrict__ root,
                                   const float* __restrict__ bias,
                                   const float* __restrict__ acc,
                                   const float* __restrict__ deg,
                                   float* __restrict__ h, int Nx_) {
  int lane = threadIdx.x & 63;
  int n = (int)((blockIdx.x * blockDim.x + threadIdx.x) >> 6);
  if (n >= Nx_) return;
  float xs = x[(size_t)n * CIN + lane];
  float r = 0.f;
#pragma unroll 4
  for (int i = 0; i < CIN; i++) {
    float xv = __shfl(xs, i, 64);
    r = fmaf(xv, root[i * COUT + lane], r);
  }
  float d = deg[n];
  d = d > 1.f ? d : 1.f;
  float o = acc[(size_t)n * COUT + lane] / d + r + bias[lane];
  h[(size_t)n * COUT + lane] = (o > 0.f) ? o : expm1f(o);
}

// ---------- kNN pre-pack: [x0,x1,x2,|x|^2] ----------
__global__ void pack_posx_kernel(const float* __restrict__ pos_x,
                                 float4* __restrict__ pxp, int Nx_) {
  int t = blockIdx.x * blockDim.x + threadIdx.x;
  if (t >= Nx_) return;
  float a0 = pos_x[t * 3 + 0], a1 = pos_x[t * 3 + 1], a2 = pos_x[t * 3 + 2];
  pxp[t] = make_float4(a0, a1, a2, a0 * a0 + a1 * a1 + a2 * a2);
}

// ---------- fused kNN + inverse-distance interp (k<=3 gated path) ----------
__global__ void knn_interp2_kernel(const float* __restrict__ h,
                                   const float4* __restrict__ pxp,
                                   const float* __restrict__ pos_y,
                                   const int* __restrict__ batch_x,
                                   const int* __restrict__ batch_y,
                                   const int* __restrict__ kptr,
                                   float* __restrict__ out,
                                   int Nx_, int Ny_) {
  int lane = threadIdx.x & 63;
  int yy = (int)((blockIdx.x * blockDim.x + threadIdx.x) >> 6);
  if (yy >= Ny_) return;

  float q0 = pos_y[yy * 3 + 0], q1 = pos_y[yy * 3 + 1], q2 = pos_y[yy * 3 + 2];
  float py2 = q0 * q0 + q1 * q1 + q2 * q2;
  int by = batch_y[yy];
  int kk = *kptr;
  kk = kk < 1 ? 1 : (kk > 8 ? 8 : kk);

  float num = 0.f, den = 0.f;

  if (kk <= 3) {
    const float FINF = __uint_as_float(0x7f800000u);
    float bd0 = FINF, bd1 = FINF, bd2 = FINF;
    unsigned bi0 = ~0u, bi1 = ~0u, bi2 = ~0u;
    float U = FINF;  // wave-min of lane 3rd-best: safe skip bound

    for (int t0 = 0; t0 < Nx_; t0 += 64) {
      int t = t0 + lane;
      int tc = t < Nx_ ? t : Nx_ - 1;
      float4 p = pxp[tc];
      float dot = fmaf(q0, p.x, fmaf(q1, p.y, q2 * p.z));
      float d2 = fmaf(-2.f, dot, py2 + p.w);
      if (batch_x[tc] != by) d2 = 1e10f;
      if (t >= Nx_) d2 = FINF;

      if (__any(d2 < U)) {
        float kv = d2;
        unsigned ki = (unsigned)t;
        {
          bool lt = kv < bd0;
          float nv = lt ? kv : bd0; float xv = lt ? bd0 : kv;
          unsigned ni = lt ? ki : bi0; unsigned xi = lt ? bi0 : ki;
          bd0 = nv; bi0 = ni; kv = xv; ki = xi;
        }
        {
          bool lt = kv < bd1;
          float nv = lt ? kv : bd1; float xv = lt ? bd1 : kv;
          unsigned ni = lt ? ki : bi1; unsigned xi = lt ? bi1 : ki;
          bd1 = nv; bi1 = ni; kv = xv; ki = xi;
        }
        {
          bool lt = kv < bd2;
          float nv = lt ? kv : bd2;
          unsigned ni = lt ? ki : bi2;
          bd2 = nv; bi2 = ni;
        }
      }
      if ((t0 & 448) == 448) U = wmin64f(bd2);
    }

    unsigned long long c0 = (((unsigned long long)f32_orderable(bd0)) << 32) | bi0;
    unsigned long long c1 = (((unsigned long long)f32_orderable(bd1)) << 32) | bi1;
    unsigned long long c2 = (((unsigned long long)f32_orderable(bd2)) << 32) | bi2;

    for (int j = 0; j < kk; j++) {
      unsigned long long m = wmin64(c0);
      if (c0 == m) { c0 = c1; c1 = c2; c2 = ~0ull; }
      unsigned u = (unsigned)(m >> 32);
      int idx = (int)(m & 0xffffffffu);
      idx = (idx < 0 || idx >= Nx_) ? 0 : idx;
      float d2 = f32_unorderable(u);
      float w = 1.f / fmaxf(d2, 1e-16f);
      num = fmaf(w, h[(size_t)idx * COUT + lane], num);
      den += w;
    }
  } else {
    unsigned long long best[8];
#pragma unroll
    for (int j = 0; j < 8; j++) best[j] = ~0ull;

    for (int t0 = 0; t0 < Nx_; t0 += 64) {
      int t = t0 + lane;
      unsigned long long key = ~0ull;
      if (t < Nx_) {
        float4 p = pxp[t];
        float dot = fmaf(q0, p.x, fmaf(q1, p.y, q2 * p.z));
        float d2 = fmaf(-2.f, dot, py2 + p.w);
        if (batch_x[t] != by) d2 = 1e10f;
        key = (((unsigned long long)f32_orderable(d2)) << 32) | (unsigned)t;
      }
      if (key < best[7]) {
#pragma unroll
        for (int j = 0; j < 8; j++) {
          unsigned long long mn = key < best[j] ? key : best[j];
          unsigned long long mx = key < best[j] ? best[j] : key;
          best[j] = mn;
          key = mx;
        }
      }
    }

    for (int j = 0; j < kk; j++) {
      unsigned long long m = wmin64(best[0]);
      if (best[0] == m) {
#pragma unroll
        for (int t = 0; t < 7; t++) best[t] = best[t + 1];
        best[7] = ~0ull;
      }
      unsigned u = (unsigned)(m >> 32);
      int idx = (int)(m & 0xffffffffu);
      idx = (idx < 0 || idx >= Nx_) ? 0 : idx;
      float d2 = f32_unorderable(u);
      float w = 1.f / fmaxf(d2, 1e-16f);
      num = fmaf(w, h[(size_t)idx * COUT + lane], num);
      den += w;
    }
  }

  out[(size_t)yy * COUT + lane] = num / den;
}

extern "C" void kernel_launch(void* const* d_in, const int* in_sizes, int n_in,
                              void* d_out, int out_size, void* d_ws, size_t ws_size,
                              hipStream_t stream) {
  const float* x = (const float*)d_in[0];
  const float* pos_x = (const float*)d_in[1];
  const float* pos_y = (const float*)d_in[2];
  const int* eidx = (const int*)d_in[3];
  const float* pseudo = (const float*)d_in[4];
  const int* batch_x = (const int*)d_in[5];
  const int* batch_y = (const int*)d_in[6];
  const float* W = (const float*)d_in[7];   // [125,64,64]
  const float* root = (const float*)d_in[8];
  const float* bias = (const float*)d_in[9];
  const int* kptr = (const int*)d_in[10];

  int Nx = in_sizes[0] / CIN;
  int Ny = in_sizes[2] / 3;
  int E = in_sizes[3] / 2;

  // ws layout: acc[Nx*64]f | deg[Nx]f | h[Nx*64]f | pxp[Nx*4]f |
  //            xbf[Nx*64]u16 | wbf[125*4096]u16 | xw[Nx*125*64]u16
  float* acc = (float*)d_ws;
  float* deg = acc + (size_t)Nx * COUT;
  float* h = deg + Nx;
  float4* pxp = (float4*)(h + (size_t)Nx * COUT);
  unsigned short* xbf = (unsigned short*)(pxp + Nx);
  unsigned short* wbf = xbf + (size_t)Nx * CIN;
  unsigned short* xw = wbf + (size_t)KTOT * CIN * COUT;

  float* out = (float*)d_out;

  hipMemsetAsync(acc, 0, ((size_t)Nx * COUT + Nx) * sizeof(float), stream);

  {
    int n4 = Nx * CIN / 4;
    cvtx_kernel<<<(n4 + 255) / 256, 256, 0, stream>>>(x, xbf, n4);
  }
  cvtw_kernel<<<KTOT, 256, 0, stream>>>(W, wbf);
  {
    dim3 grid((Nx + 63) / 64, KTOT);
    xw_mfma_kernel<<<grid, 256, 0, stream>>>(xbf, wbf, xw, Nx);
  }
  {
    int blocks = (E * WAVE + 255) / 256;
    edge_sum_kernel<<<blocks, 256, 0, stream>>>(eidx, pseudo, xw, acc, deg, E);
  }
  {
    int blocks = (Nx * WAVE + 255) / 256;
    node_finish_kernel<<<blocks, 256, 0, stream>>>(x, root, bias, acc, deg, h, Nx);
  }
  pack_posx_kernel<<<(Nx + 255) / 256, 256, 0, stream>>>(pos_x, pxp, Nx);
  {
    int blocks = (Ny * WAVE + 255) / 256;
    knn_interp2_kernel<<<blocks, 256, 0, stream>>>(h, pxp, pos_y, batch_x, batch_y,
                                                   kptr, out, Nx, Ny);
  }
}

// Round 10
// 141.325 us; speedup vs baseline: 1.1898x; 1.0713x over previous
//
#include <hip/hip_runtime.h>
#include <stdint.h>

#define WAVE 64
#define CIN 64
#define COUT 64
#define KS 5
#define KTOT 125   // 5^3
#define NSPLIT 16  // kNN candidate splits (3*NSPLIT must be <= 64)
#define BM 1e5f    // batch fold scale: BM*BM = 1e10 (reference mismatch penalty)

typedef __attribute__((ext_vector_type(8))) short short8v;  // 8 bf16 = 4 VGPRs
typedef __attribute__((ext_vector_type(4))) float f32x4;

__device__ inline unsigned long long wmin64(unsigned long long v) {
#pragma unroll
  for (int o = 32; o >= 1; o >>= 1) {
    unsigned long long u = __shfl_xor(v, o, 64);
    v = (u < v) ? u : v;
  }
  return v;
}

__device__ inline unsigned f32_orderable(float f) {
  unsigned fb = __float_as_uint(f);
  return (fb & 0x80000000u) ? ~fb : (fb | 0x80000000u);
}
__device__ inline float f32_unorderable(unsigned u) {
  unsigned fb = (u & 0x80000000u) ? (u & 0x7fffffffu) : ~u;
  return __uint_as_float(fb);
}

__device__ inline unsigned short f2bf(float f) {  // RNE
  unsigned u = __float_as_uint(f);
  unsigned r = (u + 0x7fffu + ((u >> 16) & 1u)) >> 16;
  return (unsigned short)r;
}
__device__ inline float bf2f(unsigned short v) {
  return __uint_as_float(((unsigned)v) << 16);
}

__device__ inline void edge_basis(const float* __restrict__ pseudo, int e,
                                  float bas[8], int kidx[8]) {
  float v0 = pseudo[e * 3 + 0] * (float)(KS - 1);
  float v1 = pseudo[e * 3 + 1] * (float)(KS - 1);
  float v2 = pseudo[e * 3 + 2] * (float)(KS - 1);
  float l0 = floorf(v0), l1 = floorf(v1), l2 = floorf(v2);
  float f0 = v0 - l0, f1 = v1 - l1, f2 = v2 - l2;
  int i0 = (int)l0, i1 = (int)l1, i2 = (int)l2;
#pragma unroll
  for (int s = 0; s < 8; s++) {
    int b0 = s & 1, b1 = (s >> 1) & 1, b2 = (s >> 2) & 1;
    float bb = (b0 ? f0 : 1.f - f0) * (b1 ? f1 : 1.f - f1) * (b2 ? f2 : 1.f - f2);
    int j0 = i0 + b0; j0 = j0 < 0 ? 0 : (j0 > KS - 1 ? KS - 1 : j0);
    int j1 = i1 + b1; j1 = j1 < 0 ? 0 : (j1 > KS - 1 ? KS - 1 : j1);
    int j2 = i2 + b2; j2 = j2 < 0 ? 0 : (j2 > KS - 1 ? KS - 1 : j2);
    bas[s] = bb;
    kidx[s] = j0 + KS * j1 + KS * KS * j2;
  }
}

// ---------- C0: x -> bf16 ----------
__global__ void cvtx_kernel(const float* __restrict__ x,
                            unsigned short* __restrict__ xbf, int n4) {
  int i = blockIdx.x * blockDim.x + threadIdx.x;
  if (i >= n4) return;
  float4 v = *(const float4*)&x[i * 4];
  *(ushort4*)&xbf[i * 4] =
      make_ushort4(f2bf(v.x), f2bf(v.y), f2bf(v.z), f2bf(v.w));
}

// ---------- C1: W[k][i][o] -> wbf[k][o][i] bf16 ----------
__global__ __launch_bounds__(256) void cvtw_kernel(const float* __restrict__ Wf,
                                                   unsigned short* __restrict__ wbf) {
  __shared__ float L[64][68];
  int k = blockIdx.x;
  int tid = threadIdx.x;
  {
    int i = tid >> 2, o0 = (tid & 3) * 16;
    const float* src = Wf + (size_t)k * 4096 + i * 64 + o0;
    float4 a = *(const float4*)src;
    float4 b = *(const float4*)(src + 4);
    float4 c = *(const float4*)(src + 8);
    float4 d = *(const float4*)(src + 12);
    *(float4*)&L[i][o0 + 0] = a;
    *(float4*)&L[i][o0 + 4] = b;
    *(float4*)&L[i][o0 + 8] = c;
    *(float4*)&L[i][o0 + 12] = d;
  }
  __syncthreads();
  int o = tid >> 2, i0 = (tid & 3) * 16;
  unsigned short* dst = wbf + (size_t)k * 4096 + o * 64 + i0;
#pragma unroll
  for (int g = 0; g < 4; g++) {
    *(ushort4*)&dst[g * 4] =
        make_ushort4(f2bf(L[i0 + g * 4 + 0][o]), f2bf(L[i0 + g * 4 + 1][o]),
                     f2bf(L[i0 + g * 4 + 2][o]), f2bf(L[i0 + g * 4 + 3][o]));
  }
}

// ---------- S1: xw[n,k,:] = x[n] @ W[k] via MFMA ----------
__global__ __launch_bounds__(256) void xw_mfma_kernel(
    const unsigned short* __restrict__ xbf,
    const unsigned short* __restrict__ wbf,
    unsigned short* __restrict__ xw, int Nx_) {
  int tid = threadIdx.x;
  int w = tid >> 6, lane = tid & 63;
  int n0 = blockIdx.x * 64;
  int k = blockIdx.y;
  int row16 = n0 + w * 16;

  int lr = lane & 15, kg = lane >> 4;
  int rA = row16 + lr;
  if (rA >= Nx_) rA = Nx_ - 1;

  short8v a0 = *(const short8v*)&xbf[(size_t)rA * CIN + kg * 8];
  short8v a1 = *(const short8v*)&xbf[(size_t)rA * CIN + 32 + kg * 8];

  const unsigned short* wb = wbf + (size_t)k * 4096;
  f32x4 acc[4];
#pragma unroll
  for (int ct = 0; ct < 4; ct++) {
    int col = ct * 16 + lr;
    short8v b0 = *(const short8v*)&wb[col * 64 + kg * 8];
    short8v b1 = *(const short8v*)&wb[col * 64 + 32 + kg * 8];
    f32x4 c = {0.f, 0.f, 0.f, 0.f};
    c = __builtin_amdgcn_mfma_f32_16x16x32_bf16(a0, b0, c, 0, 0, 0);
    c = __builtin_amdgcn_mfma_f32_16x16x32_bf16(a1, b1, c, 0, 0, 0);
    acc[ct] = c;
  }

#pragma unroll
  for (int ct = 0; ct < 4; ct++) {
#pragma unroll
    for (int r = 0; r < 4; r++) {
      int row = row16 + kg * 4 + r;
      if (row < Nx_) {
        xw[((size_t)row * KTOT + k) * COUT + ct * 16 + lr] = f2bf(acc[ct][r]);
      }
    }
  }
}

// ---------- S2: per-edge gather-sum + single atomic burst ----------
__global__ void edge_sum_kernel(const int* __restrict__ ei,
                                const float* __restrict__ pseudo,
                                const unsigned short* __restrict__ xw,
                                float* __restrict__ acc,
                                float* __restrict__ deg, int E_) {
  int lane = threadIdx.x & 63;
  int e = (int)((blockIdx.x * blockDim.x + threadIdx.x) >> 6);
  if (e >= E_) return;
  int src = ei[e];
  int dst = ei[E_ + e];
  float bas[8];
  int kidx[8];
  edge_basis(pseudo, e, bas, kidx);

  const unsigned short* bx = xw + (size_t)src * (KTOT * COUT) + lane;
  float y = 0.f;
#pragma unroll
  for (int s = 0; s < 8; s++) {
    y = fmaf(bas[s], bf2f(bx[kidx[s] * COUT]), y);
  }
  atomicAdd(&acc[(size_t)dst * COUT + lane], y);
  if (lane == 0) atomicAdd(&deg[dst], 1.f);
}

// ---------- node finish ----------
__global__ void node_finish_kernel(const float* __restrict__ x,
                                   const float* __restrict__ root,
                                   const float* __restrict__ bias,
                                   const float* __restrict__ acc,
                                   const float* __restrict__ deg,
                                   float* __restrict__ h, int Nx_) {
  int lane = threadIdx.x & 63;
  int n = (int)((blockIdx.x * blockDim.x + threadIdx.x) >> 6);
  if (n >= Nx_) return;
  float xs = x[(size_t)n * CIN + lane];
  float r = 0.f;
#pragma unroll 4
  for (int i = 0; i < CIN; i++) {
    float xv = __shfl(xs, i, 64);
    r = fmaf(xv, root[i * COUT + lane], r);
  }
  float d = deg[n];
  d = d > 1.f ? d : 1.f;
  float o = acc[(size_t)n * COUT + lane] / d + r + bias[lane];
  h[(size_t)n * COUT + lane] = (o > 0.f) ? o : expm1f(o);
}

// ---------- kNN pre-pack: [c0,c1,c2, px2 + (bx*BM)^2] and bx*BM ----------
__global__ void pack_posx_kernel(const float* __restrict__ pos_x,
                                 const int* __restrict__ batch_x,
                                 float4* __restrict__ pxp4,
                                 float* __restrict__ pxb, int Nx_) {
  int t = blockIdx.x * blockDim.x + threadIdx.x;
  if (t >= Nx_) return;
  float a0 = pos_x[t * 3 + 0], a1 = pos_x[t * 3 + 1], a2 = pos_x[t * 3 + 2];
  float bm = (float)batch_x[t] * BM;
  pxp4[t] = make_float4(a0, a1, a2,
                        a0 * a0 + a1 * a1 + a2 * a2 + bm * bm);
  pxb[t] = bm;
}

// ---------- kNN partial: one query per LANE, candidates via LDS broadcast ----------
__global__ __launch_bounds__(256) void knn_part_kernel(
    const float4* __restrict__ pxp4, const float* __restrict__ pxb,
    const float* __restrict__ pos_y, const int* __restrict__ batch_y,
    const int* __restrict__ kptr, unsigned long long* __restrict__ part,
    int Nx_, int Ny_, int csize) {
  if (*kptr > 3) return;  // generic path handles
  __shared__ float4 lc[256];
  __shared__ float lb[256];
  const float FINF = __uint_as_float(0x7f800000u);

  int tid = threadIdx.x;
  int split = blockIdx.y;
  int base0 = split * csize;

  int qy = blockIdx.x * 256 + tid;
  int qc = qy < Ny_ ? qy : Ny_ - 1;
  float q0 = pos_y[qc * 3 + 0], q1 = pos_y[qc * 3 + 1], q2 = pos_y[qc * 3 + 2];
  float q3 = (float)batch_y[qc] * BM;
  float py2t = q0 * q0 + q1 * q1 + q2 * q2 + q3 * q3;

  float bd0 = FINF, bd1 = FINF, bd2 = FINF;
  unsigned bi0 = ~0u, bi1 = ~0u, bi2 = ~0u;

  for (int tb = 0; tb < csize; tb += 256) {
    int t = base0 + tb + tid;
    float4 cv;
    float cb;
    if (t < Nx_) {
      cv = pxp4[t];
      cb = pxb[t];
    } else {
      cv = make_float4(0.f, 0.f, 0.f, FINF);  // d2 = +inf, never inserted
      cb = 0.f;
    }
    __syncthreads();  // previous tile's reads done
    lc[tid] = cv;
    lb[tid] = cb;
    __syncthreads();

#pragma unroll 4
    for (int j = 0; j < 256; j++) {
      float4 c = lc[j];   // same addr across lanes -> LDS broadcast
      float c3 = lb[j];
      float dot = fmaf(q0, c.x, fmaf(q1, c.y, fmaf(q2, c.z, q3 * c3)));
      float d2 = fmaf(-2.f, dot, py2t + c.w);
      if (d2 < bd2) {  // exec-masked; skips when no lane inserts
        float kv = d2;
        unsigned ki = (unsigned)(base0 + tb + j);
        {
          bool lt = kv < bd0;
          float nv = lt ? kv : bd0; float xv = lt ? bd0 : kv;
          unsigned ni = lt ? ki : bi0; unsigned xi = lt ? bi0 : ki;
          bd0 = nv; bi0 = ni; kv = xv; ki = xi;
        }
        {
          bool lt = kv < bd1;
          float nv = lt ? kv : bd1; float xv = lt ? bd1 : kv;
          unsigned ni = lt ? ki : bi1; unsigned xi = lt ? bi1 : ki;
          bd1 = nv; bi1 = ni; kv = xv; ki = xi;
        }
        {
          bool lt = kv < bd2;
          bd2 = lt ? kv : bd2;
          bi2 = lt ? ki : bi2;
        }
      }
    }
  }

  if (qy < Ny_) {
    unsigned long long* pp = part + ((size_t)split * Ny_ + qy) * 3;
    pp[0] = (((unsigned long long)f32_orderable(bd0)) << 32) | bi0;
    pp[1] = (((unsigned long long)f32_orderable(bd1)) << 32) | bi1;
    pp[2] = (((unsigned long long)f32_orderable(bd2)) << 32) | bi2;
  }
}

// ---------- kNN merge + interp: wave per query, 3*NSPLIT entries ----------
__global__ void knn_merge_kernel(const unsigned long long* __restrict__ part,
                                 const float* __restrict__ h,
                                 const int* __restrict__ kptr,
                                 float* __restrict__ out, int Nx_, int Ny_) {
  int kk = *kptr;
  if (kk > 3) return;  // generic path handles
  kk = kk < 1 ? 1 : kk;
  int lane = threadIdx.x & 63;
  int qy = (int)((blockIdx.x * blockDim.x + threadIdx.x) >> 6);
  if (qy >= Ny_) return;

  unsigned long long key = ~0ull;
  if (lane < 3 * NSPLIT) {
    key = part[((size_t)(lane / 3) * Ny_ + qy) * 3 + (lane % 3)];
  }

  float num = 0.f, den = 0.f;
  for (int i = 0; i < kk; i++) {
    unsigned long long m = wmin64(key);
    if (key == m) key = ~0ull;  // keys unique (disjoint idx per split)
    unsigned u = (unsigned)(m >> 32);
    int idx = (int)(m & 0xffffffffu);
    idx = (idx < 0 || idx >= Nx_) ? 0 : idx;
    float d2 = f32_unorderable(u);
    float w = 1.f / fmaxf(d2, 1e-16f);
    num = fmaf(w, h[(size_t)idx * COUT + lane], num);
    den += w;
  }
  out[(size_t)qy * COUT + lane] = num / den;
}

// ---------- generic k>3 fallback (wave per query, top-8) ----------
__global__ void knn_generic_kernel(const float* __restrict__ h,
                                   const float4* __restrict__ pxp4,
                                   const float* __restrict__ pxb,
                                   const float* __restrict__ pos_y,
                                   const int* __restrict__ batch_y,
                                   const int* __restrict__ kptr,
                                   float* __restrict__ out,
                                   int Nx_, int Ny_) {
  int kk = *kptr;
  if (kk <= 3) return;  // fast path handles
  kk = kk > 8 ? 8 : kk;
  int lane = threadIdx.x & 63;
  int yy = (int)((blockIdx.x * blockDim.x + threadIdx.x) >> 6);
  if (yy >= Ny_) return;

  float q0 = pos_y[yy * 3 + 0], q1 = pos_y[yy * 3 + 1], q2 = pos_y[yy * 3 + 2];
  float q3 = (float)batch_y[yy] * BM;
  float py2t = q0 * q0 + q1 * q1 + q2 * q2 + q3 * q3;

  unsigned long long best[8];
#pragma unroll
  for (int j = 0; j < 8; j++) best[j] = ~0ull;

  for (int t0 = 0; t0 < Nx_; t0 += 64) {
    int t = t0 + lane;
    unsigned long long key = ~0ull;
    if (t < Nx_) {
      float4 p = pxp4[t];
      float c3 = pxb[t];
      float dot = fmaf(q0, p.x, fmaf(q1, p.y, fmaf(q2, p.z, q3 * c3)));
      float d2 = fmaf(-2.f, dot, py2t + p.w);
      key = (((unsigned long long)f32_orderable(d2)) << 32) | (unsigned)t;
    }
    if (key < best[7]) {
#pragma unroll
      for (int j = 0; j < 8; j++) {
        unsigned long long mn = key < best[j] ? key : best[j];
        unsigned long long mx = key < best[j] ? best[j] : key;
        best[j] = mn;
        key = mx;
      }
    }
  }

  float num = 0.f, den = 0.f;
  for (int j = 0; j < kk; j++) {
    unsigned long long m = wmin64(best[0]);
    if (best[0] == m) {
#pragma unroll
      for (int t = 0; t < 7; t++) best[t] = best[t + 1];
      best[7] = ~0ull;
    }
    unsigned u = (unsigned)(m >> 32);
    int idx = (int)(m & 0xffffffffu);
    idx = (idx < 0 || idx >= Nx_) ? 0 : idx;
    float d2 = f32_unorderable(u);
    float w = 1.f / fmaxf(d2, 1e-16f);
    num = fmaf(w, h[(size_t)idx * COUT + lane], num);
    den += w;
  }
  out[(size_t)yy * COUT + lane] = num / den;
}

extern "C" void kernel_launch(void* const* d_in, const int* in_sizes, int n_in,
                              void* d_out, int out_size, void* d_ws, size_t ws_size,
                              hipStream_t stream) {
  const float* x = (const float*)d_in[0];
  const float* pos_x = (const float*)d_in[1];
  const float* pos_y = (const float*)d_in[2];
  const int* eidx = (const int*)d_in[3];
  const float* pseudo = (const float*)d_in[4];
  const int* batch_x = (const int*)d_in[5];
  const int* batch_y = (const int*)d_in[6];
  const float* W = (const float*)d_in[7];   // [125,64,64]
  const float* root = (const float*)d_in[8];
  const float* bias = (const float*)d_in[9];
  const int* kptr = (const int*)d_in[10];

  int Nx = in_sizes[0] / CIN;
  int Ny = in_sizes[2] / 3;
  int E = in_sizes[3] / 2;

  // candidate chunk per split, multiple of 256
  int csize = ((Nx + NSPLIT - 1) / NSPLIT + 255) & ~255;
  if (csize < 256) csize = 256;

  // ws layout: acc[Nx*64]f | deg[Nx]f | h[Nx*64]f | pxp4[Nx]float4 | pxb[Nx]f |
  //            xbf[Nx*64]u16 | wbf[125*4096]u16 | xw[Nx*125*64]u16 | part[NSPLIT*Ny*3]u64
  float* acc = (float*)d_ws;
  float* deg = acc + (size_t)Nx * COUT;
  float* h = deg + Nx;
  float4* pxp4 = (float4*)(h + (size_t)Nx * COUT);
  float* pxb = (float*)(pxp4 + Nx);
  unsigned short* xbf = (unsigned short*)(pxb + Nx);
  unsigned short* wbf = xbf + (size_t)Nx * CIN;
  unsigned short* xw = wbf + (size_t)KTOT * CIN * COUT;
  uintptr_t paddr = (uintptr_t)(xw + (size_t)Nx * KTOT * COUT);
  paddr = (paddr + 7) & ~(uintptr_t)7;
  unsigned long long* part = (unsigned long long*)paddr;

  float* out = (float*)d_out;

  hipMemsetAsync(acc, 0, ((size_t)Nx * COUT + Nx) * sizeof(float), stream);

  {
    int n4 = Nx * CIN / 4;
    cvtx_kernel<<<(n4 + 255) / 256, 256, 0, stream>>>(x, xbf, n4);
  }
  cvtw_kernel<<<KTOT, 256, 0, stream>>>(W, wbf);
  {
    dim3 grid((Nx + 63) / 64, KTOT);
    xw_mfma_kernel<<<grid, 256, 0, stream>>>(xbf, wbf, xw, Nx);
  }
  {
    int blocks = (E * WAVE + 255) / 256;
    edge_sum_kernel<<<blocks, 256, 0, stream>>>(eidx, pseudo, xw, acc, deg, E);
  }
  {
    int blocks = (Nx * WAVE + 255) / 256;
    node_finish_kernel<<<blocks, 256, 0, stream>>>(x, root, bias, acc, deg, h, Nx);
  }
  pack_posx_kernel<<<(Nx + 255) / 256, 256, 0, stream>>>(pos_x, batch_x, pxp4, pxb, Nx);
  {
    dim3 grid((Ny + 255) / 256, NSPLIT);
    knn_part_kernel<<<grid, 256, 0, stream>>>(pxp4, pxb, pos_y, batch_y, kptr,
                                              part, Nx, Ny, csize);
  }
  {
    int blocks = (Ny * WAVE + 255) / 256;
    knn_merge_kernel<<<blocks, 256, 0, stream>>>(part, h, kptr, out, Nx, Ny);
    knn_generic_kernel<<<blocks, 256, 0, stream>>>(h, pxp4, pxb, pos_y, batch_y,
                                                   kptr, out, Nx, Ny);
  }
}

// Round 11
// 138.109 us; speedup vs baseline: 1.2175x; 1.0233x over previous
//
#include <hip/hip_runtime.h>
#include <stdint.h>

#define WAVE 64
#define CIN 64
#define COUT 64
#define KS 5
#define KTOT 125   // 5^3
#define NSPLIT 16  // kNN candidate splits (3*NSPLIT must be <= 64)
#define BM 1e5f    // batch fold scale: BM*BM = 1e10 (reference mismatch penalty)

typedef __attribute__((ext_vector_type(8))) short short8v;  // 8 bf16 = 4 VGPRs
typedef __attribute__((ext_vector_type(4))) float f32x4;

__device__ inline unsigned long long wmin64(unsigned long long v) {
#pragma unroll
  for (int o = 32; o >= 1; o >>= 1) {
    unsigned long long u = __shfl_xor(v, o, 64);
    v = (u < v) ? u : v;
  }
  return v;
}

__device__ inline unsigned f32_orderable(float f) {
  unsigned fb = __float_as_uint(f);
  return (fb & 0x80000000u) ? ~fb : (fb | 0x80000000u);
}
__device__ inline float f32_unorderable(unsigned u) {
  unsigned fb = (u & 0x80000000u) ? (u & 0x7fffffffu) : ~u;
  return __uint_as_float(fb);
}

__device__ inline unsigned short f2bf(float f) {  // RNE
  unsigned u = __float_as_uint(f);
  unsigned r = (u + 0x7fffu + ((u >> 16) & 1u)) >> 16;
  return (unsigned short)r;
}
__device__ inline float bf2f(unsigned short v) {
  return __uint_as_float(((unsigned)v) << 16);
}

__device__ inline void edge_basis(const float* __restrict__ pseudo, int e,
                                  float bas[8], int kidx[8]) {
  float v0 = pseudo[e * 3 + 0] * (float)(KS - 1);
  float v1 = pseudo[e * 3 + 1] * (float)(KS - 1);
  float v2 = pseudo[e * 3 + 2] * (float)(KS - 1);
  float l0 = floorf(v0), l1 = floorf(v1), l2 = floorf(v2);
  float f0 = v0 - l0, f1 = v1 - l1, f2 = v2 - l2;
  int i0 = (int)l0, i1 = (int)l1, i2 = (int)l2;
#pragma unroll
  for (int s = 0; s < 8; s++) {
    int b0 = s & 1, b1 = (s >> 1) & 1, b2 = (s >> 2) & 1;
    float bb = (b0 ? f0 : 1.f - f0) * (b1 ? f1 : 1.f - f1) * (b2 ? f2 : 1.f - f2);
    int j0 = i0 + b0; j0 = j0 < 0 ? 0 : (j0 > KS - 1 ? KS - 1 : j0);
    int j1 = i1 + b1; j1 = j1 < 0 ? 0 : (j1 > KS - 1 ? KS - 1 : j1);
    int j2 = i2 + b2; j2 = j2 < 0 ? 0 : (j2 > KS - 1 ? KS - 1 : j2);
    bas[s] = bb;
    kidx[s] = j0 + KS * j1 + KS * KS * j2;
  }
}

// ---------- C0: x -> bf16 ----------
__global__ void cvtx_kernel(const float* __restrict__ x,
                            unsigned short* __restrict__ xbf, int n4) {
  int i = blockIdx.x * blockDim.x + threadIdx.x;
  if (i >= n4) return;
  float4 v = *(const float4*)&x[i * 4];
  *(ushort4*)&xbf[i * 4] =
      make_ushort4(f2bf(v.x), f2bf(v.y), f2bf(v.z), f2bf(v.w));
}

// ---------- C1: W[k][i][o] -> wbf[k][o][i] bf16 ----------
__global__ __launch_bounds__(256) void cvtw_kernel(const float* __restrict__ Wf,
                                                   unsigned short* __restrict__ wbf) {
  __shared__ float L[64][68];
  int k = blockIdx.x;
  int tid = threadIdx.x;
  {
    int i = tid >> 2, o0 = (tid & 3) * 16;
    const float* src = Wf + (size_t)k * 4096 + i * 64 + o0;
    float4 a = *(const float4*)src;
    float4 b = *(const float4*)(src + 4);
    float4 c = *(const float4*)(src + 8);
    float4 d = *(const float4*)(src + 12);
    *(float4*)&L[i][o0 + 0] = a;
    *(float4*)&L[i][o0 + 4] = b;
    *(float4*)&L[i][o0 + 8] = c;
    *(float4*)&L[i][o0 + 12] = d;
  }
  __syncthreads();
  int o = tid >> 2, i0 = (tid & 3) * 16;
  unsigned short* dst = wbf + (size_t)k * 4096 + o * 64 + i0;
#pragma unroll
  for (int g = 0; g < 4; g++) {
    *(ushort4*)&dst[g * 4] =
        make_ushort4(f2bf(L[i0 + g * 4 + 0][o]), f2bf(L[i0 + g * 4 + 1][o]),
                     f2bf(L[i0 + g * 4 + 2][o]), f2bf(L[i0 + g * 4 + 3][o]));
  }
}

// ---------- S1: xw[n,k,:] = x[n] @ W[k] via MFMA + LDS-staged coalesced stores ----------
__global__ __launch_bounds__(256) void xw_mfma_kernel(
    const unsigned short* __restrict__ xbf,
    const unsigned short* __restrict__ wbf,
    unsigned short* __restrict__ xw, int Nx_) {
  __shared__ unsigned short S[64][64];  // block's 64-row x 64-col bf16 tile
  int tid = threadIdx.x;
  int w = tid >> 6, lane = tid & 63;
  int n0 = blockIdx.x * 64;
  int k = blockIdx.y;

  int lr = lane & 15, kg = lane >> 4;
  int rA = n0 + w * 16 + lr;
  if (rA >= Nx_) rA = Nx_ - 1;

  short8v a0 = *(const short8v*)&xbf[(size_t)rA * CIN + kg * 8];
  short8v a1 = *(const short8v*)&xbf[(size_t)rA * CIN + 32 + kg * 8];

  const unsigned short* wb = wbf + (size_t)k * 4096;
#pragma unroll
  for (int ct = 0; ct < 4; ct++) {
    int col = ct * 16 + lr;
    short8v b0 = *(const short8v*)&wb[col * 64 + kg * 8];
    short8v b1 = *(const short8v*)&wb[col * 64 + 32 + kg * 8];
    f32x4 c = {0.f, 0.f, 0.f, 0.f};
    c = __builtin_amdgcn_mfma_f32_16x16x32_bf16(a0, b0, c, 0, 0, 0);
    c = __builtin_amdgcn_mfma_f32_16x16x32_bf16(a1, b1, c, 0, 0, 0);
    // D: col = ct*16 + (lane&15), row_local = w*16 + kg*4 + reg
#pragma unroll
    for (int r = 0; r < 4; r++) {
      S[w * 16 + kg * 4 + r][ct * 16 + lr] = f2bf(c[r]);
    }
  }
  __syncthreads();

  // coalesced store: per instruction 8 rows x 16B/lane = 8 full 128B rows
#pragma unroll
  for (int round = 0; round < 2; round++) {
    int rr = (tid >> 3) + round * 32;   // local row
    int ch = (tid & 7) * 8;             // ushort offset within row
    int grow = n0 + rr;
    if (grow < Nx_) {
      uint4 v = *(const uint4*)&S[rr][ch];
      *(uint4*)&xw[((size_t)grow * KTOT + k) * COUT + ch] = v;
    }
  }
}

// ---------- S2: per-edge gather-sum + single atomic burst ----------
__global__ void edge_sum_kernel(const int* __restrict__ ei,
                                const float* __restrict__ pseudo,
                                const unsigned short* __restrict__ xw,
                                float* __restrict__ acc,
                                float* __restrict__ deg, int E_) {
  int lane = threadIdx.x & 63;
  int e = (int)((blockIdx.x * blockDim.x + threadIdx.x) >> 6);
  if (e >= E_) return;
  int src = ei[e];
  int dst = ei[E_ + e];
  float bas[8];
  int kidx[8];
  edge_basis(pseudo, e, bas, kidx);

  const unsigned short* bx = xw + (size_t)src * (KTOT * COUT) + lane;
  float y = 0.f;
#pragma unroll
  for (int s = 0; s < 8; s++) {
    y = fmaf(bas[s], bf2f(bx[kidx[s] * COUT]), y);
  }
  atomicAdd(&acc[(size_t)dst * COUT + lane], y);
  if (lane == 0) atomicAdd(&deg[dst], 1.f);
}

// ---------- node finish ----------
__global__ void node_finish_kernel(const float* __restrict__ x,
                                   const float* __restrict__ root,
                                   const float* __restrict__ bias,
                                   const float* __restrict__ acc,
                                   const float* __restrict__ deg,
                                   float* __restrict__ h, int Nx_) {
  int lane = threadIdx.x & 63;
  int n = (int)((blockIdx.x * blockDim.x + threadIdx.x) >> 6);
  if (n >= Nx_) return;
  float xs = x[(size_t)n * CIN + lane];
  float r = 0.f;
#pragma unroll 4
  for (int i = 0; i < CIN; i++) {
    float xv = __shfl(xs, i, 64);
    r = fmaf(xv, root[i * COUT + lane], r);
  }
  float d = deg[n];
  d = d > 1.f ? d : 1.f;
  float o = acc[(size_t)n * COUT + lane] / d + r + bias[lane];
  h[(size_t)n * COUT + lane] = (o > 0.f) ? o : expm1f(o);
}

// ---------- kNN pre-pack: [c0,c1,c2, px2 + (bx*BM)^2] and bx*BM ----------
__global__ void pack_posx_kernel(const float* __restrict__ pos_x,
                                 const int* __restrict__ batch_x,
                                 float4* __restrict__ pxp4,
                                 float* __restrict__ pxb, int Nx_) {
  int t = blockIdx.x * blockDim.x + threadIdx.x;
  if (t >= Nx_) return;
  float a0 = pos_x[t * 3 + 0], a1 = pos_x[t * 3 + 1], a2 = pos_x[t * 3 + 2];
  float bm = (float)batch_x[t] * BM;
  pxp4[t] = make_float4(a0, a1, a2,
                        a0 * a0 + a1 * a1 + a2 * a2 + bm * bm);
  pxb[t] = bm;
}

// ---------- kNN partial: one query per LANE, candidates via LDS broadcast ----------
__global__ __launch_bounds__(256) void knn_part_kernel(
    const float4* __restrict__ pxp4, const float* __restrict__ pxb,
    const float* __restrict__ pos_y, const int* __restrict__ batch_y,
    const int* __restrict__ kptr, unsigned long long* __restrict__ part,
    int Nx_, int Ny_, int csize) {
  if (*kptr > 3) return;  // generic path handles
  __shared__ float4 lc[256];
  __shared__ float lb[256];
  const float FINF = __uint_as_float(0x7f800000u);

  int tid = threadIdx.x;
  int split = blockIdx.y;
  int base0 = split * csize;

  int qy = blockIdx.x * 256 + tid;
  int qc = qy < Ny_ ? qy : Ny_ - 1;
  float q0 = pos_y[qc * 3 + 0], q1 = pos_y[qc * 3 + 1], q2 = pos_y[qc * 3 + 2];
  float q3 = (float)batch_y[qc] * BM;
  float py2t = q0 * q0 + q1 * q1 + q2 * q2 + q3 * q3;

  float bd0 = FINF, bd1 = FINF, bd2 = FINF;
  unsigned bi0 = ~0u, bi1 = ~0u, bi2 = ~0u;

  for (int tb = 0; tb < csize; tb += 256) {
    int t = base0 + tb + tid;
    float4 cv;
    float cb;
    if (t < Nx_) {
      cv = pxp4[t];
      cb = pxb[t];
    } else {
      cv = make_float4(0.f, 0.f, 0.f, FINF);  // d2 = +inf, never inserted
      cb = 0.f;
    }
    __syncthreads();
    lc[tid] = cv;
    lb[tid] = cb;
    __syncthreads();

#pragma unroll 4
    for (int j = 0; j < 256; j++) {
      float4 c = lc[j];  // same addr across lanes -> LDS broadcast
      float c3 = lb[j];
      float dot = fmaf(q0, c.x, fmaf(q1, c.y, fmaf(q2, c.z, q3 * c3)));
      float d2 = fmaf(-2.f, dot, py2t + c.w);
      if (d2 < bd2) {  // exec-masked
        float kv = d2;
        unsigned ki = (unsigned)(base0 + tb + j);
        {
          bool lt = kv < bd0;
          float nv = lt ? kv : bd0; float xv = lt ? bd0 : kv;
          unsigned ni = lt ? ki : bi0; unsigned xi = lt ? bi0 : ki;
          bd0 = nv; bi0 = ni; kv = xv; ki = xi;
        }
        {
          bool lt = kv < bd1;
          float nv = lt ? kv : bd1; float xv = lt ? bd1 : kv;
          unsigned ni = lt ? ki : bi1; unsigned xi = lt ? bi1 : ki;
          bd1 = nv; bi1 = ni; kv = xv; ki = xi;
        }
        {
          bool lt = kv < bd2;
          bd2 = lt ? kv : bd2;
          bi2 = lt ? ki : bi2;
        }
      }
    }
  }

  if (qy < Ny_) {
    unsigned long long* pp = part + ((size_t)split * Ny_ + qy) * 3;
    pp[0] = (((unsigned long long)f32_orderable(bd0)) << 32) | bi0;
    pp[1] = (((unsigned long long)f32_orderable(bd1)) << 32) | bi1;
    pp[2] = (((unsigned long long)f32_orderable(bd2)) << 32) | bi2;
  }
}

// ---------- kNN merge + interp: wave per query, 3*NSPLIT entries ----------
__global__ void knn_merge_kernel(const unsigned long long* __restrict__ part,
                                 const float* __restrict__ h,
                                 const int* __restrict__ kptr,
                                 float* __restrict__ out, int Nx_, int Ny_) {
  int kk = *kptr;
  if (kk > 3) return;  // generic path handles
  kk = kk < 1 ? 1 : kk;
  int lane = threadIdx.x & 63;
  int qy = (int)((blockIdx.x * blockDim.x + threadIdx.x) >> 6);
  if (qy >= Ny_) return;

  unsigned long long key = ~0ull;
  if (lane < 3 * NSPLIT) {
    key = part[((size_t)(lane / 3) * Ny_ + qy) * 3 + (lane % 3)];
  }

  float num = 0.f, den = 0.f;
  for (int i = 0; i < kk; i++) {
    unsigned long long m = wmin64(key);
    if (key == m) key = ~0ull;  // keys unique (disjoint idx per split)
    unsigned u = (unsigned)(m >> 32);
    int idx = (int)(m & 0xffffffffu);
    idx = (idx < 0 || idx >= Nx_) ? 0 : idx;
    float d2 = f32_unorderable(u);
    float w = 1.f / fmaxf(d2, 1e-16f);
    num = fmaf(w, h[(size_t)idx * COUT + lane], num);
    den += w;
  }
  out[(size_t)qy * COUT + lane] = num / den;
}

// ---------- generic k>3 fallback (wave per query, top-8) ----------
__global__ void knn_generic_kernel(const float* __restrict__ h,
                                   const float4* __restrict__ pxp4,
                                   const float* __restrict__ pxb,
                                   const float* __restrict__ pos_y,
                                   const int* __restrict__ batch_y,
                                   const int* __restrict__ kptr,
                                   float* __restrict__ out,
                                   int Nx_, int Ny_) {
  int kk = *kptr;
  if (kk <= 3) return;  // fast path handles
  kk = kk > 8 ? 8 : kk;
  int lane = threadIdx.x & 63;
  int yy = (int)((blockIdx.x * blockDim.x + threadIdx.x) >> 6);
  if (yy >= Ny_) return;

  float q0 = pos_y[yy * 3 + 0], q1 = pos_y[yy * 3 + 1], q2 = pos_y[yy * 3 + 2];
  float q3 = (float)batch_y[yy] * BM;
  float py2t = q0 * q0 + q1 * q1 + q2 * q2 + q3 * q3;

  unsigned long long best[8];
#pragma unroll
  for (int j = 0; j < 8; j++) best[j] = ~0ull;

  for (int t0 = 0; t0 < Nx_; t0 += 64) {
    int t = t0 + lane;
    unsigned long long key = ~0ull;
    if (t < Nx_) {
      float4 p = pxp4[t];
      float c3 = pxb[t];
      float dot = fmaf(q0, p.x, fmaf(q1, p.y, fmaf(q2, p.z, q3 * c3)));
      float d2 = fmaf(-2.f, dot, py2t + p.w);
      key = (((unsigned long long)f32_orderable(d2)) << 32) | (unsigned)t;
    }
    if (key < best[7]) {
#pragma unroll
      for (int j = 0; j < 8; j++) {
        unsigned long long mn = key < best[j] ? key : best[j];
        unsigned long long mx = key < best[j] ? best[j] : key;
        best[j] = mn;
        key = mx;
      }
    }
  }

  float num = 0.f, den = 0.f;
  for (int j = 0; j < kk; j++) {
    unsigned long long m = wmin64(best[0]);
    if (best[0] == m) {
#pragma unroll
      for (int t = 0; t < 7; t++) best[t] = best[t + 1];
      best[7] = ~0ull;
    }
    unsigned u = (unsigned)(m >> 32);
    int idx = (int)(m & 0xffffffffu);
    idx = (idx < 0 || idx >= Nx_) ? 0 : idx;
    float d2 = f32_unorderable(u);
    float w = 1.f / fmaxf(d2, 1e-16f);
    num = fmaf(w, h[(size_t)idx * COUT + lane], num);
    den += w;
  }
  out[(size_t)yy * COUT + lane] = num / den;
}

extern "C" void kernel_launch(void* const* d_in, const int* in_sizes, int n_in,
                              void* d_out, int out_size, void* d_ws, size_t ws_size,
                              hipStream_t stream) {
  const float* x = (const float*)d_in[0];
  const float* pos_x = (const float*)d_in[1];
  const float* pos_y = (const float*)d_in[2];
  const int* eidx = (const int*)d_in[3];
  const float* pseudo = (const float*)d_in[4];
  const int* batch_x = (const int*)d_in[5];
  const int* batch_y = (const int*)d_in[6];
  const float* W = (const float*)d_in[7];   // [125,64,64]
  const float* root = (const float*)d_in[8];
  const float* bias = (const float*)d_in[9];
  const int* kptr = (const int*)d_in[10];

  int Nx = in_sizes[0] / CIN;
  int Ny = in_sizes[2] / 3;
  int E = in_sizes[3] / 2;

  int csize = ((Nx + NSPLIT - 1) / NSPLIT + 255) & ~255;
  if (csize < 256) csize = 256;

  // ws layout: acc[Nx*64]f | deg[Nx]f | h[Nx*64]f | pxp4[Nx]float4 | pxb[Nx]f |
  //            xbf[Nx*64]u16 | wbf[125*4096]u16 | xw[Nx*125*64]u16 | part[NSPLIT*Ny*3]u64
  float* acc = (float*)d_ws;
  float* deg = acc + (size_t)Nx * COUT;
  float* h = deg + Nx;
  float4* pxp4 = (float4*)(h + (size_t)Nx * COUT);
  float* pxb = (float*)(pxp4 + Nx);
  unsigned short* xbf = (unsigned short*)(pxb + Nx);
  unsigned short* wbf = xbf + (size_t)Nx * CIN;
  unsigned short* xw = wbf + (size_t)KTOT * CIN * COUT;
  uintptr_t paddr = (uintptr_t)(xw + (size_t)Nx * KTOT * COUT);
  paddr = (paddr + 7) & ~(uintptr_t)7;
  unsigned long long* part = (unsigned long long*)paddr;

  float* out = (float*)d_out;

  hipMemsetAsync(acc, 0, ((size_t)Nx * COUT + Nx) * sizeof(float), stream);

  {
    int n4 = Nx * CIN / 4;
    cvtx_kernel<<<(n4 + 255) / 256, 256, 0, stream>>>(x, xbf, n4);
  }
  cvtw_kernel<<<KTOT, 256, 0, stream>>>(W, wbf);
  {
    dim3 grid((Nx + 63) / 64, KTOT);
    xw_mfma_kernel<<<grid, 256, 0, stream>>>(xbf, wbf, xw, Nx);
  }
  {
    int blocks = (E * WAVE + 255) / 256;
    edge_sum_kernel<<<blocks, 256, 0, stream>>>(eidx, pseudo, xw, acc, deg, E);
  }
  {
    int blocks = (Nx * WAVE + 255) / 256;
    node_finish_kernel<<<blocks, 256, 0, stream>>>(x, root, bias, acc, deg, h, Nx);
  }
  pack_posx_kernel<<<(Nx + 255) / 256, 256, 0, stream>>>(pos_x, batch_x, pxp4, pxb, Nx);
  {
    dim3 grid((Ny + 255) / 256, NSPLIT);
    knn_part_kernel<<<grid, 256, 0, stream>>>(pxp4, pxb, pos_y, batch_y, kptr,
                                              part, Nx, Ny, csize);
  }
  {
    int blocks = (Ny * WAVE + 255) / 256;
    knn_merge_kernel<<<blocks, 256, 0, stream>>>(part, h, kptr, out, Nx, Ny);
    knn_generic_kernel<<<blocks, 256, 0, stream>>>(h, pxp4, pxb, pos_y, batch_y,
                                                   kptr, out, Nx, Ny);
  }
}